// Round 7
// baseline (444.456 us; speedup 1.0000x reference)
//
#include <hip/hip_runtime.h>
#include <hip/hip_bf16.h>
#include <math.h>

// ---------------------------------------------------------------------------
// GCN: 3x GCNConv(128->128) + fused (Wp1@Wp2) head + log_softmax.
// Round 7: split-gather load balancing (32 lanes/node, two halves of the edge
// list, shfl_xor combine) -> block makespan = max(d_i/2) not max(d_i); the
// round-6 barrier cost 3.59->2.68 TB/s on the gather. CSR scatter chunk
// 8192->2048 (784 blocks, 4x shorter LDS-atomic chains).
// ---------------------------------------------------------------------------

#define DH 128    // feature dim (D == H == 128)
#define NC 40     // classes
#define BN 256    // nodes per bucket
#define MAXNB 512 // max buckets (N <= 131072)
#define CH 2048   // edges per scatter block
#define ECAP 6144 // LDS edge capacity in bucket_csr
#define SP 136    // LDS row stride (elems): 128 + 8 pad

typedef __attribute__((ext_vector_type(8))) short bf16x8;
typedef __attribute__((ext_vector_type(4))) float f32x4;

__device__ __forceinline__ unsigned short f2bf(float f) {
    unsigned u = __float_as_uint(f);
    unsigned r = (u + 0x7fffu + ((u >> 16) & 1u)) >> 16;   // RNE
    return (unsigned short)r;
}
__device__ __forceinline__ unsigned pack2(float lo, float hi) {
    return (unsigned)f2bf(lo) | ((unsigned)f2bf(hi) << 16);
}

// ---------------- bucket-level histogram (LDS, then coalesced merge) --------

__global__ __launch_bounds__(256) void bucket_hist(const int* __restrict__ dst, int E,
                                                   unsigned* __restrict__ bcnt) {
    __shared__ unsigned h[MAXNB];
    int tid = threadIdx.x;
    for (int i = tid; i < MAXNB; i += 256) h[i] = 0;
    __syncthreads();
    int e0 = blockIdx.x * CH;
    int e1 = min(e0 + CH, E);
    for (int i = e0 + tid; i < e1; i += 256)
        atomicAdd(&h[dst[i] >> 8], 1u);
    __syncthreads();
    for (int i = tid; i < MAXNB; i += 256)
        if (h[i]) atomicAdd(&bcnt[i], h[i]);
}

__global__ __launch_bounds__(256) void bucket_alloc(const unsigned* __restrict__ bcnt,
                                                    unsigned* __restrict__ bbase,
                                                    unsigned* __restrict__ bpos,
                                                    unsigned* __restrict__ cursor, int NB) {
    int i = blockIdx.x * 256 + threadIdx.x;
    if (i < NB) {
        unsigned c = bcnt[i];
        unsigned o = atomicAdd(cursor, c);
        bbase[i] = o;
        bpos[i] = o;
    }
}

__global__ __launch_bounds__(256) void bucket_scatter(const int* __restrict__ src,
                                                      const int* __restrict__ dst, int E,
                                                      unsigned* __restrict__ bpos,
                                                      unsigned* __restrict__ ebuf) {
    __shared__ unsigned hist[MAXNB];
    __shared__ unsigned lbase[MAXNB];
    __shared__ unsigned gbase[MAXNB];
    __shared__ unsigned cur[MAXNB];
    __shared__ unsigned sorted[CH];
    __shared__ unsigned short sbkt[CH];
    __shared__ unsigned total;

    int tid = threadIdx.x;
    int e0 = blockIdx.x * CH;
    int nE = min(CH, E - e0);

    for (int i = tid; i < MAXNB; i += 256) { hist[i] = 0; cur[i] = 0; }
    if (tid == 0) total = 0;
    __syncthreads();

    for (int i = tid; i < nE; i += 256)
        atomicAdd(&hist[dst[e0 + i] >> 8], 1u);
    __syncthreads();

    for (int i = tid; i < MAXNB; i += 256) {
        unsigned h = hist[i];
        lbase[i] = h ? atomicAdd(&total, h) : 0u;
        gbase[i] = h ? atomicAdd(&bpos[i], h) : 0u;
    }
    __syncthreads();

    for (int i = tid; i < nE; i += 256) {
        int s = src[e0 + i];
        int d = dst[e0 + i];
        unsigned b = (unsigned)d >> 8;
        unsigned r = atomicAdd(&cur[b], 1u);
        unsigned p = lbase[b] + r;
        sorted[p] = ((unsigned)s << 8) | ((unsigned)d & 255u);
        sbkt[p] = (unsigned short)b;
    }
    __syncthreads();

    for (int p = tid; p < nE; p += 256) {
        unsigned b = sbkt[p];
        ebuf[gbase[b] + (p - lbase[b])] = sorted[p];
    }
}

__global__ __launch_bounds__(256) void bucket_csr(const unsigned* __restrict__ ebuf,
                                                  const unsigned* __restrict__ bbase,
                                                  const unsigned* __restrict__ bcnt,
                                                  unsigned* __restrict__ off,
                                                  unsigned* __restrict__ cnt,
                                                  float* __restrict__ nrm,
                                                  int* __restrict__ csr, int N) {
    __shared__ unsigned h[BN];
    __shared__ unsigned nb[BN];
    __shared__ unsigned ncur[BN];
    __shared__ int lcsr[ECAP];
    __shared__ unsigned tot;

    int b = blockIdx.x;
    int tid = threadIdx.x;
    unsigned ebase = bbase[b];
    unsigned ecnt = bcnt[b];

    h[tid] = 0;
    if (tid == 0) tot = 0;
    __syncthreads();

    for (unsigned i = tid; i < ecnt; i += 256)
        atomicAdd(&h[ebuf[ebase + i] & 255u], 1u);
    __syncthreads();

    unsigned myh = h[tid];
    unsigned mybase = myh ? atomicAdd(&tot, myh) : 0u;
    nb[tid] = mybase;
    ncur[tid] = 0;
    int node = b * BN + tid;
    if (node < N) {
        off[node] = ebase + mybase;
        cnt[node] = myh;
        nrm[node] = rsqrtf((float)myh + 1.0f);
    }
    __syncthreads();

    if (ecnt <= ECAP) {
        for (unsigned i = tid; i < ecnt; i += 256) {
            unsigned v = ebuf[ebase + i];
            unsigned nl = v & 255u;
            unsigned r = atomicAdd(&ncur[nl], 1u);
            lcsr[nb[nl] + r] = (int)(v >> 8);
        }
        __syncthreads();
        for (unsigned i = tid; i < ecnt; i += 256)
            csr[ebase + i] = lcsr[i];
    } else {
        for (unsigned i = tid; i < ecnt; i += 256) {
            unsigned v = ebuf[ebase + i];
            unsigned nl = v & 255u;
            unsigned r = atomicAdd(&ncur[nl], 1u);
            csr[ebase + nb[nl] + r] = (int)(v >> 8);
        }
    }
}

// ---------------- weight prep: Wt (3 layers, transposed bf16) + fused head --

__global__ __launch_bounds__(256) void prep_w(const float* __restrict__ W1,
                                              const float* __restrict__ W2,
                                              const float* __restrict__ W3,
                                              const float* __restrict__ Wp1,
                                              const float* __restrict__ bp1,
                                              const float* __restrict__ Wp2,
                                              const float* __restrict__ bp2,
                                              unsigned short* __restrict__ Wt,
                                              unsigned short* __restrict__ Wft,
                                              float* __restrict__ bfh) {
    int id = blockIdx.x * 256 + threadIdx.x;
    if (id < 3 * DH * DH) {
        int l = id >> 14, r = id & (DH * DH - 1);
        int k = r >> 7, n = r & 127;
        const float* W = (l == 0) ? W1 : (l == 1) ? W2 : W3;
        Wt[l * DH * DH + n * DH + k] = f2bf(W[k * DH + n]);
    } else if (id < 3 * DH * DH + 48 * DH) {
        int o = id - 3 * DH * DH;
        int c = o >> 7, k = o & 127;
        float acc = 0.f;
        if (c < NC)
            for (int j = 0; j < DH; ++j) acc += Wp1[k * DH + j] * Wp2[j * NC + c];
        Wft[c * DH + k] = f2bf(acc);
    } else if (id < 3 * DH * DH + 48 * DH + 48) {
        int c = id - 3 * DH * DH - 48 * DH;
        float acc = 0.f;
        if (c < NC) {
            acc = bp2[c];
            for (int j = 0; j < DH; ++j) acc += bp1[j] * Wp2[j * NC + c];
        }
        bfh[c] = acc;
    }
}

// ---------------- layer-1 MFMA GEMM: Ab = bf16(nrm * (x_f32 @ W1)) ----------

__global__ __launch_bounds__(256) void gemm_mfma_f32(const float* __restrict__ X,
                                                     const unsigned short* __restrict__ Wt,
                                                     const float* __restrict__ nrm,
                                                     unsigned short* __restrict__ outb,
                                                     int nrows) {
    const int tid = threadIdx.x;
    const int wave = tid >> 6;
    const int lane = tid & 63;
    const int m = lane & 15;
    const int quad = lane >> 4;
    const int rbase = blockIdx.x * 128 + wave * 32;

    union U8 { bf16x8 v; unsigned u[4]; };

    f32x4 acc[2][8];
#pragma unroll
    for (int rt = 0; rt < 2; ++rt)
#pragma unroll
        for (int ct = 0; ct < 8; ++ct) acc[rt][ct] = (f32x4){0.f, 0.f, 0.f, 0.f};

#pragma unroll
    for (int kt = 0; kt < 4; ++kt) {
        const int kof = kt * 32 + quad * 8;
        bf16x8 a[2], b[8];
#pragma unroll
        for (int rt = 0; rt < 2; ++rt) {
            int r = rbase + rt * 16 + m;
            r = (r < nrows) ? r : (nrows - 1);
            const float* p = X + (size_t)r * DH + kof;
            float4 u0 = *(const float4*)p;
            float4 u1 = *(const float4*)(p + 4);
            U8 t;
            t.u[0] = pack2(u0.x, u0.y);
            t.u[1] = pack2(u0.z, u0.w);
            t.u[2] = pack2(u1.x, u1.y);
            t.u[3] = pack2(u1.z, u1.w);
            a[rt] = t.v;
        }
#pragma unroll
        for (int ct = 0; ct < 8; ++ct)
            b[ct] = *(const bf16x8*)(Wt + (ct * 16 + m) * DH + kof);
#pragma unroll
        for (int rt = 0; rt < 2; ++rt)
#pragma unroll
            for (int ct = 0; ct < 8; ++ct)
                acc[rt][ct] = __builtin_amdgcn_mfma_f32_16x16x32_bf16(a[rt], b[ct], acc[rt][ct], 0, 0, 0);
    }

#pragma unroll
    for (int rt = 0; rt < 2; ++rt)
#pragma unroll
        for (int reg = 0; reg < 4; ++reg) {
            int r = rbase + rt * 16 + quad * 4 + reg;
            if (r < nrows) {
                float s = nrm[r];
#pragma unroll
                for (int ct = 0; ct < 8; ++ct)
                    outb[(size_t)r * DH + ct * 16 + m] = f2bf(acc[rt][ct][reg] * s);
            }
        }
}

// ---------------- split gather phase (512-thread blocks) --------------------
// 32 lanes/node: two 16-lane halves each take half the edge list, fp32 accum,
// combine via shfl_xor(.,16) (halves are 16 lanes apart in the same wave).
// Result: z = relu(nrm*(sum+self)+bias) cast bf16 into sA[16][SP].

__device__ __forceinline__ void bf8_add(float* acc, uint4 v) {
    acc[0] += __uint_as_float(v.x << 16);
    acc[1] += __uint_as_float(v.x & 0xffff0000u);
    acc[2] += __uint_as_float(v.y << 16);
    acc[3] += __uint_as_float(v.y & 0xffff0000u);
    acc[4] += __uint_as_float(v.z << 16);
    acc[5] += __uint_as_float(v.z & 0xffff0000u);
    acc[6] += __uint_as_float(v.w << 16);
    acc[7] += __uint_as_float(v.w & 0xffff0000u);
}

__device__ __forceinline__ void gather_phase(const uint4* __restrict__ Abf,
                                             const int* __restrict__ csr,
                                             const unsigned* __restrict__ off,
                                             const unsigned* __restrict__ cnt,
                                             const float* __restrict__ nrm,
                                             const float* __restrict__ bias,
                                             unsigned short (*sA)[SP], int N) {
    const int tid = threadIdx.x;
    const int g = tid >> 5;          // node group 0..15
    const int l32 = tid & 31;
    const int half = l32 >> 4;       // which half of the edge list
    const int lane = l32 & 15;       // column lane (8 bf16 cols)
    const int node = blockIdx.x * 16 + g;

    if (node < N) {
        float acc[8];
        unsigned o = off[node];
        unsigned d = cnt[node];

        if (half == 0) {
            uint4 v = Abf[(size_t)node * 16 + lane];   // self term
            acc[0] = __uint_as_float(v.x << 16);
            acc[1] = __uint_as_float(v.x & 0xffff0000u);
            acc[2] = __uint_as_float(v.y << 16);
            acc[3] = __uint_as_float(v.y & 0xffff0000u);
            acc[4] = __uint_as_float(v.z << 16);
            acc[5] = __uint_as_float(v.z & 0xffff0000u);
            acc[6] = __uint_as_float(v.w << 16);
            acc[7] = __uint_as_float(v.w & 0xffff0000u);
        } else {
#pragma unroll
            for (int c = 0; c < 8; ++c) acc[c] = 0.f;
        }

        unsigned e  = (d * (unsigned)half) >> 1;
        unsigned e1 = (d * (unsigned)(half + 1)) >> 1;
        for (; e + 4 <= e1; e += 4) {
            int s0 = csr[o + e + 0];
            int s1 = csr[o + e + 1];
            int s2 = csr[o + e + 2];
            int s3 = csr[o + e + 3];
            uint4 v0 = Abf[(size_t)s0 * 16 + lane];
            uint4 v1 = Abf[(size_t)s1 * 16 + lane];
            uint4 v2 = Abf[(size_t)s2 * 16 + lane];
            uint4 v3 = Abf[(size_t)s3 * 16 + lane];
            bf8_add(acc, v0);
            bf8_add(acc, v1);
            bf8_add(acc, v2);
            bf8_add(acc, v3);
        }
        for (; e < e1; ++e) {
            int s = csr[o + e];
            uint4 v = Abf[(size_t)s * 16 + lane];
            bf8_add(acc, v);
        }

        // combine the two halves (lanes l and l^16 hold partials of same node)
#pragma unroll
        for (int c = 0; c < 8; ++c) acc[c] += __shfl_xor(acc[c], 16);

        if (half == 0) {
            float nm = nrm[node];
            float4 b0 = *(const float4*)(bias + lane * 8);
            float4 b1 = *(const float4*)(bias + lane * 8 + 4);
            unsigned short* p = &sA[g][lane * 8];
            p[0] = f2bf(fmaxf(acc[0] * nm + b0.x, 0.f));
            p[1] = f2bf(fmaxf(acc[1] * nm + b0.y, 0.f));
            p[2] = f2bf(fmaxf(acc[2] * nm + b0.z, 0.f));
            p[3] = f2bf(fmaxf(acc[3] * nm + b0.w, 0.f));
            p[4] = f2bf(fmaxf(acc[4] * nm + b1.x, 0.f));
            p[5] = f2bf(fmaxf(acc[5] * nm + b1.y, 0.f));
            p[6] = f2bf(fmaxf(acc[6] * nm + b1.z, 0.f));
            p[7] = f2bf(fmaxf(acc[7] * nm + b1.w, 0.f));
        }
    }
    __syncthreads();
}

// ---------------- fused: aggregate + next-layer GEMM (512 threads) ----------
// Phase 2: 8 waves, wave w = col-tile w (16x16); out = bf16(nrm[r]*(z @ W)).

__global__ __launch_bounds__(512) void agg_gemm(const uint4* __restrict__ Abf,
                                                const int* __restrict__ csr,
                                                const unsigned* __restrict__ off,
                                                const unsigned* __restrict__ cnt,
                                                const float* __restrict__ nrm,
                                                const float* __restrict__ bias,
                                                const unsigned short* __restrict__ Wt,
                                                unsigned short* __restrict__ outb, int N) {
    __shared__ unsigned short sA[16][SP];
    gather_phase(Abf, csr, off, cnt, nrm, bias, sA, N);

    const int tid = threadIdx.x;
    const int wave = tid >> 6;          // col tile 0..7
    const int l64 = tid & 63;
    const int m = l64 & 15;
    const int quad = l64 >> 4;

    f32x4 acc = (f32x4){0.f, 0.f, 0.f, 0.f};
#pragma unroll
    for (int kt = 0; kt < 4; ++kt) {
        const int kof = kt * 32 + quad * 8;
        bf16x8 a = *(const bf16x8*)&sA[m][kof];
        bf16x8 b = *(const bf16x8*)(Wt + (wave * 16 + m) * DH + kof);
        acc = __builtin_amdgcn_mfma_f32_16x16x32_bf16(a, b, acc, 0, 0, 0);
    }

#pragma unroll
    for (int reg = 0; reg < 4; ++reg) {
        int r = blockIdx.x * 16 + quad * 4 + reg;
        if (r < N)
            outb[(size_t)r * DH + wave * 16 + m] = f2bf(acc[reg] * nrm[r]);
    }
}

// ---------------- fused: aggregate + head GEMM + log_softmax ----------------

__global__ __launch_bounds__(512) void agg_head(const uint4* __restrict__ Abf,
                                                const int* __restrict__ csr,
                                                const unsigned* __restrict__ off,
                                                const unsigned* __restrict__ cnt,
                                                const float* __restrict__ nrm,
                                                const float* __restrict__ bias,
                                                const unsigned short* __restrict__ Wft,
                                                const float* __restrict__ bfh,
                                                float* __restrict__ out, int N) {
    __shared__ unsigned short sA[16][SP];
    gather_phase(Abf, csr, off, cnt, nrm, bias, sA, N);

    const int tid = threadIdx.x;
    if (tid >= 64) return;                 // one wave does the 16x48 head
    const int m = tid & 15;
    const int quad = tid >> 4;

    f32x4 acc[3];
#pragma unroll
    for (int ct = 0; ct < 3; ++ct) acc[ct] = (f32x4){0.f, 0.f, 0.f, 0.f};

#pragma unroll
    for (int kt = 0; kt < 4; ++kt) {
        const int kof = kt * 32 + quad * 8;
        bf16x8 a = *(const bf16x8*)&sA[m][kof];
#pragma unroll
        for (int ct = 0; ct < 3; ++ct) {
            bf16x8 b = *(const bf16x8*)(Wft + (ct * 16 + m) * DH + kof);
            acc[ct] = __builtin_amdgcn_mfma_f32_16x16x32_bf16(a, b, acc[ct], 0, 0, 0);
        }
    }

    float bias0 = bfh[m];
    float bias1 = bfh[16 + m];
    float bias2 = bfh[32 + m];

#pragma unroll
    for (int reg = 0; reg < 4; ++reg) {
        float v0 = acc[0][reg] + bias0;
        float v1 = acc[1][reg] + bias1;
        float v2 = (m < 8) ? (acc[2][reg] + bias2) : -1e30f;
        float mx = fmaxf(fmaxf(v0, v1), v2);
#pragma unroll
        for (int dlt = 1; dlt < 16; dlt <<= 1) mx = fmaxf(mx, __shfl_xor(mx, dlt));
        float s = __expf(v0 - mx) + __expf(v1 - mx) + ((m < 8) ? __expf(v2 - mx) : 0.f);
#pragma unroll
        for (int dlt = 1; dlt < 16; dlt <<= 1) s += __shfl_xor(s, dlt);
        float ls = mx + __logf(s);
        int r = blockIdx.x * 16 + quad * 4 + reg;
        if (r < N) {
            out[(size_t)r * NC + m] = v0 - ls;
            out[(size_t)r * NC + 16 + m] = v1 - ls;
            if (m < 8) out[(size_t)r * NC + 32 + m] = v2 - ls;
        }
    }
}

// ---------------------------------------------------------------------------

extern "C" void kernel_launch(void* const* d_in, const int* in_sizes, int n_in,
                              void* d_out, int out_size, void* d_ws, size_t ws_size,
                              hipStream_t stream) {
    const float* x   = (const float*)d_in[0];
    const int*   ei  = (const int*)d_in[1];
    const float* W1  = (const float*)d_in[2];
    const float* b1  = (const float*)d_in[3];
    const float* W2  = (const float*)d_in[4];
    const float* b2  = (const float*)d_in[5];
    const float* W3  = (const float*)d_in[6];
    const float* b3  = (const float*)d_in[7];
    const float* Wp1 = (const float*)d_in[8];
    const float* bp1 = (const float*)d_in[9];
    const float* Wp2 = (const float*)d_in[10];
    const float* bp2 = (const float*)d_in[11];
    float* out = (float*)d_out;

    const int N = in_sizes[0] / DH;
    const int E = in_sizes[1] / 2;
    const int* src = ei;
    const int* dst = ei + E;
    const int NB = (N + BN - 1) / BN;

    // workspace carve (all 16B aligned)
    char* w = (char*)d_ws;
    unsigned short* Ab  = (unsigned short*)w; w += (size_t)N * DH * 2;
    unsigned short* Bb  = (unsigned short*)w; w += (size_t)N * DH * 2;
    int*      csr    = (int*)w;      w += (size_t)E * 4;
    unsigned* ebuf   = (unsigned*)w; w += (size_t)E * 4;
    unsigned* bcnt   = (unsigned*)w; w += MAXNB * 4;
    unsigned* cursor = (unsigned*)w; w += 16;
    unsigned* bbase  = (unsigned*)w; w += MAXNB * 4;
    unsigned* bpos   = (unsigned*)w; w += MAXNB * 4;
    unsigned* off    = (unsigned*)w; w += (size_t)N * 4;
    unsigned* cnt    = (unsigned*)w; w += (size_t)N * 4;
    float*    nrm    = (float*)w;    w += (size_t)N * 4;
    unsigned short* Wt  = (unsigned short*)w; w += 3 * DH * DH * 2;
    unsigned short* Wft = (unsigned short*)w; w += 48 * DH * 2;
    float*    bfh    = (float*)w;    w += 64 * 4;

    const int gC = (E + CH - 1) / CH;

    hipMemsetAsync(bcnt, 0, MAXNB * 4 + 16, stream);   // bcnt + cursor
    bucket_hist   <<<gC, 256, 0, stream>>>(dst, E, bcnt);
    bucket_alloc  <<<(NB + 255) / 256, 256, 0, stream>>>(bcnt, bbase, bpos, cursor, NB);
    bucket_scatter<<<gC, 256, 0, stream>>>(src, dst, E, bpos, ebuf);
    bucket_csr    <<<NB, 256, 0, stream>>>(ebuf, bbase, bcnt, off, cnt, nrm, csr, N);
    prep_w<<<(3 * DH * DH + 48 * DH + 48 + 255) / 256, 256, 0, stream>>>(
        W1, W2, W3, Wp1, bp1, Wp2, bp2, Wt, Wft, bfh);

    const int gG = (N + 127) / 128;
    const int gF = (N + 15) / 16;

    gemm_mfma_f32<<<gG, 256, 0, stream>>>(x, Wt, nrm, Ab, N);
    agg_gemm<<<gF, 512, 0, stream>>>((const uint4*)Ab, csr, off, cnt, nrm, b1,
                                     Wt + DH * DH, Bb, N);
    agg_gemm<<<gF, 512, 0, stream>>>((const uint4*)Bb, csr, off, cnt, nrm, b2,
                                     Wt + 2 * DH * DH, Ab, N);
    agg_head<<<gF, 512, 0, stream>>>((const uint4*)Ab, csr, off, cnt, nrm, b3,
                                     Wft, bfh, out, N);
}